// Round 6
// baseline (35.052 us; speedup 1.0000x reference)
//
#include <hip/hip_runtime.h>

#ifndef FLT_MAX
#define FLT_MAX 3.402823466e+38f
#endif

typedef float v2f __attribute__((ext_vector_type(2)));
typedef float v4f __attribute__((ext_vector_type(4)));

__device__ __forceinline__ float rlanef(float v, int j) {
    return __uint_as_float(__builtin_amdgcn_readlane(__float_as_uint(v), j));
}

__device__ __forceinline__ float sel3(int i, float a, float b, float c) {
    return i == 0 ? a : (i == 1 ? b : c);
}

// Deterministic scalar d2 (phase 2): sub,sub,sub,mul,fma,fma — element-wise
// identical to the packed phase-1 pipeline, so values are bit-identical.
__device__ __forceinline__ float d2f(float ax, float ay, float az,
                                     float bx, float by, float bz) {
    const float dx = __fsub_rn(ax, bx);
    const float dy = __fsub_rn(ay, by);
    const float dz = __fsub_rn(az, bz);
    return __builtin_fmaf(dx, dx, __builtin_fmaf(dy, dy, __fmul_rn(dz, dz)));
}

// One 64-lane wave per edge; 4 edges per 256-thread block.
// Phase 1: value-only min scan, TWO columns per packed f32 op (VOP3P
//          v_pk_add/mul/fma on gfx950) -> ~4 VALU per pair.
// Wave argmin: lowest lane attaining the wave min == lowest i.
// Phase 2: parallel recompute of row i1 (lane j holds x2[j] in regs),
//          ballot+ffs -> first j. Exact numpy argmin semantics.
__global__ __launch_bounds__(256, 8) void clustgeo_edge_kernel(
    const float* __restrict__ data,    // (N,4) f32; coords = cols 1..3
    const int*   __restrict__ clusts,  // (C,64) int (harness-converted from i64)
    const int*   __restrict__ eidx,    // (2,E)  int
    float*       __restrict__ out,     // (E,19) f32
    int E)
{
    const int wave = threadIdx.x >> 6;
    const int lane = threadIdx.x & 63;
    const int e = blockIdx.x * 4 + wave;
    if (e >= E) return;

    __shared__ float sx2[4][3][64];   // 3 KiB; per-wave private slice

    const int a = eidx[e];
    const int b = eidx[E + e];
    const int p1 = clusts[a * 64 + lane];
    const int p2 = clusts[b * 64 + lane];
    const float4 r1 = *reinterpret_cast<const float4*>(data + (size_t)p1 * 4);
    const float4 r2 = *reinterpret_cast<const float4*>(data + (size_t)p2 * 4);
    const float x1x = r1.y, x1y = r1.z, x1z = r1.w;
    const float x2x = r2.y, x2y = r2.z, x2z = r2.w;
    sx2[wave][0][lane] = x2x;
    sx2[wave][1][lane] = x2y;
    sx2[wave][2][lane] = x2z;
    // No __syncthreads(): each wave reads only its own slice; same-wave LDS
    // RAW is ordered by compiler-inserted lgkmcnt waits (validated R3-R5).

    const v4f* rx = reinterpret_cast<const v4f*>(&sx2[wave][0][0]);
    const v4f* ry = reinterpret_cast<const v4f*>(&sx2[wave][1][0]);
    const v4f* rz = reinterpret_cast<const v4f*>(&sx2[wave][2][0]);

    const v2f xx = {x1x, x1x};
    const v2f yy = {x1y, x1y};
    const v2f zz = {x1z, x1z};

    // Phase 1: packed value-only min. Two v2f accumulators (4 lanes of min)
    // break the dependence chain; min over values is order-independent.
    v2f acc01 = {FLT_MAX, FLT_MAX};
    v2f acc23 = {FLT_MAX, FLT_MAX};
    #pragma unroll 2
    for (int g = 0; g < 16; ++g) {
        const v4f X = rx[g];
        const v4f Y = ry[g];
        const v4f Z = rz[g];
        {   // columns 4g, 4g+1
            const v2f dx = xx - X.xy;
            const v2f dy = yy - Y.xy;
            const v2f dz = zz - Z.xy;
            const v2f d2 = __builtin_elementwise_fma(
                dx, dx, __builtin_elementwise_fma(dy, dy, dz * dz));
            acc01 = __builtin_elementwise_min(acc01, d2);
        }
        {   // columns 4g+2, 4g+3
            const v2f dx = xx - X.zw;
            const v2f dy = yy - Y.zw;
            const v2f dz = zz - Z.zw;
            const v2f d2 = __builtin_elementwise_fma(
                dx, dx, __builtin_elementwise_fma(dy, dy, dz * dz));
            acc23 = __builtin_elementwise_min(acc23, d2);
        }
    }
    const float rowmin = fminf(fminf(acc01.x, acc01.y), fminf(acc23.x, acc23.y));

    // Wave minimum of rowmin.
    float bm = rowmin;
    #pragma unroll
    for (int off = 32; off; off >>= 1) bm = fminf(bm, __shfl_xor(bm, off, 64));

    // Lowest lane whose row attains bm == lowest i (numpy row-major first).
    const unsigned long long mi = __ballot(rowmin == bm);
    const int i1 = (int)__ffsll(mi) - 1;

    // Phase 2: recompute row i1 across lanes (lane j owns x2[j] in regs).
    const float v1x = rlanef(x1x, i1);
    const float v1y = rlanef(x1y, i1);
    const float v1z = rlanef(x1z, i1);
    const float dj = d2f(v1x, v1y, v1z, x2x, x2y, x2z);
    const unsigned long long mj = __ballot(dj == bm);
    const int i2 = (int)__ffsll(mj) - 1;

    const float v2x = rlanef(x2x, i2);
    const float v2y = rlanef(x2y, i2);
    const float v2z = rlanef(x2z, i2);

    float dx = v1x - v2x, dy = v1y - v2y, dz = v1z - v2z;
    const float lend = sqrtf(dx * dx + dy * dy + dz * dz);
    if (lend > 0.f) { dx /= lend; dy /= lend; dz /= lend; }

    if (lane < 19) {
        float o;
        if (lane < 3)       o = sel3(lane,     v1x, v1y, v1z);
        else if (lane < 6)  o = sel3(lane - 3, v2x, v2y, v2z);
        else if (lane < 9)  o = sel3(lane - 6, dx, dy, dz);
        else if (lane == 9) o = lend;
        else {
            const int k = lane - 10;
            o = sel3(k / 3, dx, dy, dz) * sel3(k % 3, dx, dy, dz);
        }
        out[(size_t)e * 19 + lane] = o;
    }
}

extern "C" void kernel_launch(void* const* d_in, const int* in_sizes, int n_in,
                              void* d_out, int out_size, void* d_ws, size_t ws_size,
                              hipStream_t stream) {
    const float* data   = (const float*)d_in[0];
    const int*   clusts = (const int*)d_in[1];
    const int*   eidx   = (const int*)d_in[2];
    float*       out    = (float*)d_out;
    const int E = in_sizes[2] / 2;           // edge_index is (2, E)
    const int blocks = (E + 3) / 4;          // 4 edges (waves) per block
    clustgeo_edge_kernel<<<blocks, 256, 0, stream>>>(data, clusts, eidx, out, E);
}

// Round 7
// 33.250 us; speedup vs baseline: 1.0542x; 1.0542x over previous
//
#include <hip/hip_runtime.h>

#ifndef FLT_MAX
#define FLT_MAX 3.402823466e+38f
#endif

typedef float v2f __attribute__((ext_vector_type(2)));
typedef float v4f __attribute__((ext_vector_type(4)));

__device__ __forceinline__ float rlanef(float v, int l) {
    return __uint_as_float(__builtin_amdgcn_readlane(__float_as_uint(v), l));
}

__device__ __forceinline__ float sel3(int i, float a, float b, float c) {
    return i == 0 ? a : (i == 1 ? b : c);
}

// Deterministic d2: sub,sub,sub,mul,fma,fma — element-wise identical to the
// packed phase-1 pipeline, so phase-2 recomputed values are bit-identical.
__device__ __forceinline__ float d2f(float ax, float ay, float az,
                                     float bx, float by, float bz) {
    const float dx = __fsub_rn(ax, bx);
    const float dy = __fsub_rn(ay, by);
    const float dz = __fsub_rn(az, bz);
    return __builtin_fmaf(dx, dx, __builtin_fmaf(dy, dy, __fmul_rn(dz, dz)));
}

// TWO edges per 64-lane wave (lanes 0-31: edge A, lanes 32-63: edge B).
// Each half-lane owns rows {hl, hl+32} of x1 and cols {hl, hl+32} of x2.
// The j-scan's ds_read_b128 carries one address per half (2-way = free),
// broadcasting a 4-column group for BOTH edges in one LDS instruction:
// 24 DS instr/edge vs 48 — halves the LDS-pipe floor that bounded R5/R6.
__global__ __launch_bounds__(256, 8) void clustgeo_edge_kernel(
    const float* __restrict__ data,    // (N,4) f32; coords = cols 1..3
    const int*   __restrict__ clusts,  // (C,64) int (harness-converted from i64)
    const int*   __restrict__ eidx,    // (2,E)  int
    float*       __restrict__ out,     // (E,19) f32
    int E)
{
    const int wave = threadIdx.x >> 6;
    const int lane = threadIdx.x & 63;
    const int hl   = lane & 31;
    const bool hiH = lane >= 32;
    const int e  = blockIdx.x * 8 + wave * 2 + (hiH ? 1 : 0);
    const int ec = e < E ? e : (E - 1);   // all lanes stay active; store guarded

    __shared__ __align__(16) float sx2[4][2][3][64];   // [wave][half][comp][col]

    const int ca = eidx[ec];
    const int cb = eidx[E + ec];
    const int p1a = clusts[ca * 64 + hl];
    const int p1b = clusts[ca * 64 + hl + 32];
    const int p2a = clusts[cb * 64 + hl];
    const int p2b = clusts[cb * 64 + hl + 32];
    const float4 q1a = *reinterpret_cast<const float4*>(data + (size_t)p1a * 4);
    const float4 q1b = *reinterpret_cast<const float4*>(data + (size_t)p1b * 4);
    const float4 q2a = *reinterpret_cast<const float4*>(data + (size_t)p2a * 4);
    const float4 q2b = *reinterpret_cast<const float4*>(data + (size_t)p2b * 4);
    const float x1ax=q1a.y, x1ay=q1a.z, x1az=q1a.w;   // my row hl
    const float x1bx=q1b.y, x1by=q1b.z, x1bz=q1b.w;   // my row hl+32
    const float x2ax=q2a.y, x2ay=q2a.z, x2az=q2a.w;   // my col hl
    const float x2bx=q2b.y, x2by=q2b.z, x2bz=q2b.w;   // my col hl+32

    float* hbase = &sx2[wave][hiH ? 1 : 0][0][0];     // this half's slice
    hbase[hl      ] = x2ax;  hbase[hl + 32      ] = x2bx;
    hbase[hl + 64 ] = x2ay;  hbase[hl + 32 + 64 ] = x2by;
    hbase[hl + 128] = x2az;  hbase[hl + 32 + 128] = x2bz;
    // No __syncthreads(): each half-wave reads only its own slice; same-wave
    // LDS RAW is ordered by compiler-inserted lgkmcnt waits (validated R3-R6).

    const v2f xA = {x1ax, x1ax}, yA = {x1ay, x1ay}, zA = {x1az, x1az};
    const v2f xB = {x1bx, x1bx}, yB = {x1by, x1by}, zB = {x1bz, x1bz};

    // Phase 1: packed value-only min, both rows per group read.
    v2f r0c01 = {FLT_MAX, FLT_MAX}, r0c23 = {FLT_MAX, FLT_MAX};
    v2f r1c01 = {FLT_MAX, FLT_MAX}, r1c23 = {FLT_MAX, FLT_MAX};
    #pragma unroll 2
    for (int g = 0; g < 16; ++g) {
        const v4f X = *reinterpret_cast<const v4f*>(hbase + g * 4);
        const v4f Y = *reinterpret_cast<const v4f*>(hbase + 64 + g * 4);
        const v4f Z = *reinterpret_cast<const v4f*>(hbase + 128 + g * 4);
        {
            const v2f dx = xA - X.xy, dy = yA - Y.xy, dz = zA - Z.xy;
            r0c01 = __builtin_elementwise_min(r0c01,
                __builtin_elementwise_fma(dx, dx, __builtin_elementwise_fma(dy, dy, dz * dz)));
        }
        {
            const v2f dx = xA - X.zw, dy = yA - Y.zw, dz = zA - Z.zw;
            r0c23 = __builtin_elementwise_min(r0c23,
                __builtin_elementwise_fma(dx, dx, __builtin_elementwise_fma(dy, dy, dz * dz)));
        }
        {
            const v2f dx = xB - X.xy, dy = yB - Y.xy, dz = zB - Z.xy;
            r1c01 = __builtin_elementwise_min(r1c01,
                __builtin_elementwise_fma(dx, dx, __builtin_elementwise_fma(dy, dy, dz * dz)));
        }
        {
            const v2f dx = xB - X.zw, dy = yB - Y.zw, dz = zB - Z.zw;
            r1c23 = __builtin_elementwise_min(r1c23,
                __builtin_elementwise_fma(dx, dx, __builtin_elementwise_fma(dy, dy, dz * dz)));
        }
    }
    const float rm0 = fminf(fminf(r0c01.x, r0c01.y), fminf(r0c23.x, r0c23.y));
    const float rm1 = fminf(fminf(r1c01.x, r1c01.y), fminf(r1c23.x, r1c23.y));

    // Half-wave min (offsets <=16 never cross the 32-lane halves).
    float bmv = fminf(rm0, rm1);
    #pragma unroll
    for (int off = 16; off; off >>= 1) bmv = fminf(bmv, __shfl_xor(bmv, off, 64));

    // Lowest row attaining the min: check row-block 0 (rows 0-31) then block 1
    // (rows 32-63) — numpy row-major first-occurrence.
    const unsigned long long m0 = __ballot(rm0 == bmv);
    const unsigned long long m1 = __ballot(rm1 == bmv);
    const unsigned A0 = (unsigned)m0, A1 = (unsigned)m1;
    const unsigned B0 = (unsigned)(m0 >> 32), B1 = (unsigned)(m1 >> 32);
    const int i1A = A0 ? __builtin_ctz(A0) : 32 + __builtin_ctz(A1);
    const int i1B = B0 ? __builtin_ctz(B0) : 32 + __builtin_ctz(B1);

    // v1 per edge (readlane of the owning lane's row register; uniform conds).
    const float v1Ax = rlanef(i1A >= 32 ? x1bx : x1ax, i1A & 31);
    const float v1Ay = rlanef(i1A >= 32 ? x1by : x1ay, i1A & 31);
    const float v1Az = rlanef(i1A >= 32 ? x1bz : x1az, i1A & 31);
    const float v1Bx = rlanef(i1B >= 32 ? x1bx : x1ax, 32 + (i1B & 31));
    const float v1By = rlanef(i1B >= 32 ? x1by : x1ay, 32 + (i1B & 31));
    const float v1Bz = rlanef(i1B >= 32 ? x1bz : x1az, 32 + (i1B & 31));
    const float bmA = rlanef(bmv, 0);
    const float bmB = rlanef(bmv, 32);

    // Phase 2: recompute row i1 across cols (lane owns cols hl, hl+32 in regs;
    // d2f is bit-identical to phase 1, so first-match j is exact).
    const float w1x = hiH ? v1Bx : v1Ax;
    const float w1y = hiH ? v1By : v1Ay;
    const float w1z = hiH ? v1Bz : v1Az;
    const float bmw = hiH ? bmB : bmA;
    const float dj0 = d2f(w1x, w1y, w1z, x2ax, x2ay, x2az);
    const float dj1 = d2f(w1x, w1y, w1z, x2bx, x2by, x2bz);
    const unsigned long long n0 = __ballot(dj0 == bmw);
    const unsigned long long n1 = __ballot(dj1 == bmw);
    const unsigned Ca0 = (unsigned)n0, Ca1 = (unsigned)n1;
    const unsigned Cb0 = (unsigned)(n0 >> 32), Cb1 = (unsigned)(n1 >> 32);
    const int i2A = Ca0 ? __builtin_ctz(Ca0) : 32 + __builtin_ctz(Ca1);
    const int i2B = Cb0 ? __builtin_ctz(Cb0) : 32 + __builtin_ctz(Cb1);

    const float v2Ax = rlanef(i2A >= 32 ? x2bx : x2ax, i2A & 31);
    const float v2Ay = rlanef(i2A >= 32 ? x2by : x2ay, i2A & 31);
    const float v2Az = rlanef(i2A >= 32 ? x2bz : x2az, i2A & 31);
    const float v2Bx = rlanef(i2B >= 32 ? x2bx : x2ax, 32 + (i2B & 31));
    const float v2By = rlanef(i2B >= 32 ? x2by : x2ay, 32 + (i2B & 31));
    const float v2Bz = rlanef(i2B >= 32 ? x2bz : x2az, 32 + (i2B & 31));

    const float u2x = hiH ? v2Bx : v2Ax;
    const float u2y = hiH ? v2By : v2Ay;
    const float u2z = hiH ? v2Bz : v2Az;

    float dx = w1x - u2x, dy = w1y - u2y, dz = w1z - u2z;
    const float lend = sqrtf(dx * dx + dy * dy + dz * dz);
    if (lend > 0.f) { dx /= lend; dy /= lend; dz /= lend; }

    if (hl < 19 && e < E) {
        float o;
        if (hl < 3)       o = sel3(hl,     w1x, w1y, w1z);
        else if (hl < 6)  o = sel3(hl - 3, u2x, u2y, u2z);
        else if (hl < 9)  o = sel3(hl - 6, dx, dy, dz);
        else if (hl == 9) o = lend;
        else {
            const int k = hl - 10;
            o = sel3(k / 3, dx, dy, dz) * sel3(k % 3, dx, dy, dz);
        }
        out[(size_t)e * 19 + hl] = o;
    }
}

extern "C" void kernel_launch(void* const* d_in, const int* in_sizes, int n_in,
                              void* d_out, int out_size, void* d_ws, size_t ws_size,
                              hipStream_t stream) {
    const float* data   = (const float*)d_in[0];
    const int*   clusts = (const int*)d_in[1];
    const int*   eidx   = (const int*)d_in[2];
    float*       out    = (float*)d_out;
    const int E = in_sizes[2] / 2;           // edge_index is (2, E)
    const int blocks = (E + 7) / 8;          // 8 edges per block (4 waves x 2)
    clustgeo_edge_kernel<<<blocks, 256, 0, stream>>>(data, clusts, eidx, out, E);
}